// Round 2
// baseline (72.568 us; speedup 1.0000x reference)
//
#include <hip/hip_runtime.h>

// RBF layer: out[b,n] = exp(-GAMMA * (||x_b||^2 + ||w_n||^2 - 2 * x_b . w_n))
// x: (4096, 256) fp32 row-major; W: (256, 512) fp32 row-major; out: (4096, 512) fp32.
// GEMM via bf16 MFMA (16x16x32), norms in fp32-from-bf16, exp fused in epilogue.

#define GAMMA 0.5f
#define B_  4096
#define D_  256
#define N_  512
#define BM  64
#define BN  32
#define LDT 264   // LDS row stride in bf16 elems: 256 + 8 pad -> rows shift 4 banks each

typedef __attribute__((ext_vector_type(8))) short bf16x8;
typedef __attribute__((ext_vector_type(4))) float f32x4;
typedef __attribute__((ext_vector_type(4))) unsigned short u16x4;
typedef __attribute__((ext_vector_type(4))) float float4v;

__device__ __forceinline__ unsigned short f2bf(float f) {
    union { float f; unsigned int i; } u; u.f = f;
    return (unsigned short)(u.i >> 16);   // truncation; tolerance here is huge
}
__device__ __forceinline__ float bf2f(unsigned short h) {
    union { unsigned int i; float f; } u; u.i = ((unsigned int)h) << 16;
    return u.f;
}

__global__ __launch_bounds__(256, 2)
void rbf_kernel(const float* __restrict__ x, const float* __restrict__ W,
                float* __restrict__ out) {
    __shared__ unsigned short xs[BM][LDT];   // x tile, bf16 bits: xs[r][k]
    __shared__ unsigned short ws[BN][LDT];   // W tile transposed: ws[n][k]
    __shared__ float x2s[BM];
    __shared__ float w2s[BN];

    const int tid = threadIdx.x;
    const int bx = blockIdx.x;    // 0..15 : col tile (bx*BN)
    const int by = blockIdx.y;    // 0..63 : row tile (by*BM)

    // ---- stage x tile: BM x 256 fp32 -> bf16 LDS (coalesced float4 reads) ----
    {
        const float4v* xg = (const float4v*)(x + (size_t)by * BM * D_);
        for (int i = tid; i < BM * (D_ / 4); i += 256) {   // 4096 float4, 16/thread
            int r = i >> 6, c4 = i & 63;
            float4v v = xg[i];
            u16x4 p = { f2bf(v.x), f2bf(v.y), f2bf(v.z), f2bf(v.w) };
            *(u16x4*)&xs[r][c4 * 4] = p;
        }
    }

    // ---- stage W tile transposed: read 4x4 fp32 blocks, register-transpose ----
    {
        const float* Wg = W + bx * BN;
        for (int i = tid; i < (D_ / 4) * (BN / 4); i += 256) {  // 512 blocks, 2/thread
            int kb = i >> 3, nb = i & 7;
            const float* p0 = Wg + (size_t)(kb * 4) * N_ + nb * 4;
            float4v r0 = *(const float4v*)(p0);
            float4v r1 = *(const float4v*)(p0 + N_);
            float4v r2 = *(const float4v*)(p0 + 2 * N_);
            float4v r3 = *(const float4v*)(p0 + 3 * N_);
            u16x4 c0 = { f2bf(r0.x), f2bf(r1.x), f2bf(r2.x), f2bf(r3.x) };
            u16x4 c1 = { f2bf(r0.y), f2bf(r1.y), f2bf(r2.y), f2bf(r3.y) };
            u16x4 c2 = { f2bf(r0.z), f2bf(r1.z), f2bf(r2.z), f2bf(r3.z) };
            u16x4 c3 = { f2bf(r0.w), f2bf(r1.w), f2bf(r2.w), f2bf(r3.w) };
            *(u16x4*)&ws[nb * 4 + 0][kb * 4] = c0;
            *(u16x4*)&ws[nb * 4 + 1][kb * 4] = c1;
            *(u16x4*)&ws[nb * 4 + 2][kb * 4] = c2;
            *(u16x4*)&ws[nb * 4 + 3][kb * 4] = c3;
        }
    }
    __syncthreads();

    // ---- norms (fp32 accumulate over staged bf16; 4 threads per row/col) ----
    {
        int row = tid >> 2, q = tid & 3;
        float s = 0.f;
        for (int c = 0; c < 8; ++c) {
            bf16x8 v = *(const bf16x8*)&xs[row][q * 64 + c * 8];
            #pragma unroll
            for (int j = 0; j < 8; ++j) { float f = bf2f((unsigned short)v[j]); s += f * f; }
        }
        s += __shfl_xor(s, 1);
        s += __shfl_xor(s, 2);
        if (q == 0) x2s[row] = s;

        if (tid < BN * 4) {
            int col = tid >> 2;
            float t2 = 0.f;
            for (int c = 0; c < 8; ++c) {
                bf16x8 v = *(const bf16x8*)&ws[col][q * 64 + c * 8];
                #pragma unroll
                for (int j = 0; j < 8; ++j) { float f = bf2f((unsigned short)v[j]); t2 += f * f; }
            }
            t2 += __shfl_xor(t2, 1);
            t2 += __shfl_xor(t2, 2);
            if (q == 0) w2s[col] = t2;
        }
    }
    __syncthreads();

    // ---- MFMA main loop: 4 waves in 2x2; each wave owns a 32x16 sub-tile ----
    const int l = tid & 63, w = tid >> 6;
    const int wr = w >> 1, wc = w & 1;
    const int lr = l & 15, g = l >> 4;

    f32x4 acc00 = {0.f, 0.f, 0.f, 0.f};
    f32x4 acc10 = {0.f, 0.f, 0.f, 0.f};
    #pragma unroll
    for (int kk = 0; kk < 8; ++kk) {
        int ko = kk * 32 + g * 8;
        // A frag: lane holds x[row = l&15][k = (l>>4)*8 + j], contiguous ds_read_b128
        bf16x8 a0 = *(const bf16x8*)&xs[wr * 32 + lr][ko];
        bf16x8 a1 = *(const bf16x8*)&xs[wr * 32 + 16 + lr][ko];
        // B frag: lane holds W[k = (l>>4)*8 + j][col = l&15] == ws[col][k]
        bf16x8 b0 = *(const bf16x8*)&ws[wc * 16 + lr][ko];
        acc00 = __builtin_amdgcn_mfma_f32_16x16x32_bf16(a0, b0, acc00, 0, 0, 0);
        acc10 = __builtin_amdgcn_mfma_f32_16x16x32_bf16(a1, b0, acc10, 0, 0, 0);
    }

    // ---- epilogue: sq_dist -> exp, direct fp32 stores ----
    // C/D layout (m89/m91): col = lane&15, row = (lane>>4)*4 + i
    const float c2l = -(GAMMA) * 1.4426950408889634f;   // exp(-g*s) = 2^(s * c2l)
    float* outp = out + (size_t)(by * BM) * N_ + bx * BN;
    #pragma unroll
    for (int m = 0; m < 2; ++m) {
        f32x4 a = m ? acc10 : acc00;
        #pragma unroll
        for (int i = 0; i < 4; ++i) {
            int ar = wr * 32 + m * 16 + g * 4 + i;
            int ac = wc * 16 + lr;
            float s = x2s[ar] + w2s[ac] - 2.f * a[i];
            outp[(size_t)ar * N_ + ac] = exp2f(s * c2l);
        }
    }
}

extern "C" void kernel_launch(void* const* d_in, const int* in_sizes, int n_in,
                              void* d_out, int out_size, void* d_ws, size_t ws_size,
                              hipStream_t stream) {
    const float* x = (const float*)d_in[0];
    const float* W = (const float*)d_in[1];
    float* out = (float*)d_out;
    dim3 grid(N_ / BN, B_ / BM);   // (16, 64) = 1024 blocks
    rbf_kernel<<<grid, dim3(256), 0, stream>>>(x, W, out);
}

// Round 3
// 61.792 us; speedup vs baseline: 1.1744x; 1.1744x over previous
//
#include <hip/hip_runtime.h>

// RBF layer: out[b,n] = exp(-GAMMA * (||x_b||^2 + ||w_n||^2 - 2 * x_b . w_n))
// x: (4096,256) fp32; W: (256,512) fp32; out: (4096,512) fp32.
// bf16 MFMA GEMM. x tile staged in LDS (bf16); W read fp32 global->reg
// (L2-resident), converted in-flight; ||w||^2 accumulated in-register.
// XCD-chunked block swizzle: each XCD owns 8 by-tiles -> x fetched from HBM once.

#define GAMMA 0.5f
#define B_  4096
#define D_  256
#define N_  512
#define BM  64
#define BN  64
#define LDT 264   // 256 + 8 pad (bf16 elems); 528 B row = 33*16 -> b128-aligned, 4-bank row shift

typedef __attribute__((ext_vector_type(8))) short bf16x8;
typedef __attribute__((ext_vector_type(4))) float f32x4;
typedef __attribute__((ext_vector_type(4))) unsigned short u16x4;
typedef __attribute__((ext_vector_type(4))) float float4v;

__device__ __forceinline__ unsigned short f2bf(float f) {
    union { float f; unsigned int i; } u; u.f = f;
    return (unsigned short)(u.i >> 16);
}
__device__ __forceinline__ float bf2f(unsigned short h) {
    union { unsigned int i; float f; } u; u.i = ((unsigned int)h) << 16;
    return u.f;
}

__global__ __launch_bounds__(256, 4)
void rbf_kernel(const float* __restrict__ x, const float* __restrict__ W,
                float* __restrict__ out) {
    __shared__ unsigned short xs[BM][LDT];   // x tile, bf16
    __shared__ float x2s[BM];                // ||x_row||^2

    const int tid = threadIdx.x;

    // XCD-chunked swizzle (512 blocks % 8 XCDs == 0 -> bijective):
    // XCD k gets by in [8k, 8k+8), all 8 bx -> x tile HBM-fetched once, L2-shared.
    const int bid = blockIdx.x;
    const int wgid = (bid & 7) * 64 + (bid >> 3);
    const int bx = wgid & 7;    // 0..7  : col tile (bx*BN)
    const int by = wgid >> 3;   // 0..63 : row tile (by*BM)

    // ---- stage x tile: 64x256 fp32 -> bf16 LDS (coalesced float4) ----
    {
        const float4v* xg = (const float4v*)(x + (size_t)by * BM * D_);
        #pragma unroll
        for (int t = 0; t < 16; ++t) {
            int i = tid + t * 256;
            int r = i >> 6, c4 = i & 63;
            float4v v = xg[i];
            u16x4 p = { f2bf(v.x), f2bf(v.y), f2bf(v.z), f2bf(v.w) };
            *(u16x4*)&xs[r][c4 * 4] = p;
        }
    }
    __syncthreads();

    // ---- ||x||^2 from staged LDS: 4 threads per row, 64 rows = 256 threads ----
    {
        int row = tid >> 2, q = tid & 3;
        float s = 0.f;
        #pragma unroll
        for (int c = 0; c < 8; ++c) {
            bf16x8 v = *(const bf16x8*)&xs[row][q * 64 + c * 8];
            #pragma unroll
            for (int j = 0; j < 8; ++j) { float f = bf2f((unsigned short)v[j]); s += f * f; }
        }
        s += __shfl_xor(s, 1);
        s += __shfl_xor(s, 2);
        if (q == 0) x2s[row] = s;
    }
    __syncthreads();   // x2s ready (xs already ready after first barrier)

    // ---- MFMA: A from LDS, B fp32 global->reg (L2-hot), w2 in-register ----
    const int l = tid & 63, w = tid >> 6;
    const int wr = w >> 1, wc = w & 1;       // 2x2 waves, each 32x32 sub-tile
    const int lr = l & 15, g = l >> 4;

    const float* Wg = W + bx * BN + wc * 32 + lr;   // this lane's n=0 column
    float w2p0 = 0.f, w2p1 = 0.f;
    f32x4 accs[2][2] = {{{0,0,0,0},{0,0,0,0}},{{0,0,0,0},{0,0,0,0}}};

    #pragma unroll
    for (int kk = 0; kk < 8; ++kk) {
        const int k0 = kk * 32 + g * 8;
        const float* wp = Wg + (size_t)k0 * N_;
        float w0[8], w1[8];
        #pragma unroll
        for (int j = 0; j < 8; ++j) {
            w0[j] = wp[(size_t)j * N_];        // B[k0+j][col]      (64B segs over lr)
            w1[j] = wp[(size_t)j * N_ + 16];   // B[k0+j][col+16]
        }
        bf16x8 b0, b1;
        #pragma unroll
        for (int j = 0; j < 8; ++j) {
            b0[j] = (short)f2bf(w0[j]); b1[j] = (short)f2bf(w1[j]);
            w2p0 += w0[j] * w0[j];      w2p1 += w1[j] * w1[j];
        }
        bf16x8 a0 = *(const bf16x8*)&xs[wr * 32 + lr][k0];
        bf16x8 a1 = *(const bf16x8*)&xs[wr * 32 + 16 + lr][k0];
        accs[0][0] = __builtin_amdgcn_mfma_f32_16x16x32_bf16(a0, b0, accs[0][0], 0, 0, 0);
        accs[0][1] = __builtin_amdgcn_mfma_f32_16x16x32_bf16(a0, b1, accs[0][1], 0, 0, 0);
        accs[1][0] = __builtin_amdgcn_mfma_f32_16x16x32_bf16(a1, b0, accs[1][0], 0, 0, 0);
        accs[1][1] = __builtin_amdgcn_mfma_f32_16x16x32_bf16(a1, b1, accs[1][1], 0, 0, 0);
    }

    // w2 partials cover k = g*8..g*8+7 (+32 per kk): reduce across g (lanes ^16, ^32)
    w2p0 += __shfl_xor(w2p0, 16); w2p0 += __shfl_xor(w2p0, 32);
    w2p1 += __shfl_xor(w2p1, 16); w2p1 += __shfl_xor(w2p1, 32);

    // ---- epilogue: sq_dist -> exp2, fused, direct stores ----
    // C/D layout (m89/m91): col = lane&15, row = (lane>>4)*4 + i
    const float c2l = -(GAMMA) * 1.4426950408889634f;
    float* outp = out + (size_t)(by * BM) * N_ + bx * BN;
    #pragma unroll
    for (int m = 0; m < 2; ++m) {
        #pragma unroll
        for (int n = 0; n < 2; ++n) {
            float w2v = n ? w2p1 : w2p0;
            int ac = wc * 32 + n * 16 + lr;
            #pragma unroll
            for (int i = 0; i < 4; ++i) {
                int ar = wr * 32 + m * 16 + g * 4 + i;
                float s = x2s[ar] + w2v - 2.f * accs[m][n][i];
                outp[(size_t)ar * N_ + ac] = exp2f(s * c2l);
            }
        }
    }
}

extern "C" void kernel_launch(void* const* d_in, const int* in_sizes, int n_in,
                              void* d_out, int out_size, void* d_ws, size_t ws_size,
                              hipStream_t stream) {
    const float* x = (const float*)d_in[0];
    const float* W = (const float*)d_in[1];
    float* out = (float*)d_out;
    rbf_kernel<<<dim3(512), dim3(256), 0, stream>>>(x, W, out);
}